// Round 1
// baseline (584.778 us; speedup 1.0000x reference)
//
#include <hip/hip_runtime.h>

#define DI __device__ __forceinline__

typedef __bf16 bf16_t;
typedef __bf16 bf16x8 __attribute__((ext_vector_type(8)));
typedef float f32x4 __attribute__((ext_vector_type(4)));

// Problem constants
// B=64, N=512, F=64, H=128, FO=64, K=16
// Edge MLP: E(16x128) @ We1(128x128) -> relu -> @ We2(128x128) -> relu -> mean -> pooled(128)
// Node MLP: [x|pooled](192) @ Wn1(192x128) -> relu -> @ Wn2(128x64) -> out, * mask

DI bf16_t f2b(float f) {
  unsigned u = __float_as_uint(f);
  unsigned r = (u + 0x7fffu + ((u >> 16) & 1u)) >> 16;
  return __builtin_bit_cast(bf16_t, (unsigned short)r);
}
DI float b2f(bf16_t h) {
  return __uint_as_float(((unsigned)__builtin_bit_cast(unsigned short, h)) << 16);
}
DI f32x4 zero4() { f32x4 z = {0.f, 0.f, 0.f, 0.f}; return z; }

DI bf16x8 make_frag(const float* p, bool wantlo) {
  float4 v0 = *(const float4*)p;
  float4 v1 = *(const float4*)(p + 4);
  float vv[8] = {v0.x, v0.y, v0.z, v0.w, v1.x, v1.y, v1.z, v1.w};
  bf16x8 a;
#pragma unroll
  for (int j = 0; j < 8; ++j) {
    bf16_t hi = f2b(vv[j]);
    a[j] = wantlo ? f2b(vv[j] - b2f(hi)) : hi;
  }
  return a;
}

DI unsigned long long wave_min_u64(unsigned long long v) {
#pragma unroll
  for (int o = 1; o < 64; o <<= 1) {
    unsigned lo = (unsigned)(v & 0xffffffffull);
    unsigned hi = (unsigned)(v >> 32);
    unsigned olo = __shfl_xor(lo, o, 64);
    unsigned ohi = __shfl_xor(hi, o, 64);
    unsigned long long ov = (((unsigned long long)ohi) << 32) | olo;
    v = ov < v ? ov : v;
  }
  return v;
}

// ---------------- Kernel P: pack weights into split-bf16 MFMA B-fragment layout ----
// Layout: [slab s][ntile][lane][8 bf16], B'[k'=s*32+(lane>>4)*8+j][n=nt*16+(lane&15)]
// mode 0: B' = [W_hi ; W_hi]   (K' = 2K, pair with A' = [A_hi, A_lo])
// mode 1: B' = [W_hi ; W_lo]   (K' = 2K, pair with A' = [A_hi, A_hi])
__global__ void kpack(const float* __restrict__ We1, const float* __restrict__ We2,
                      const float* __restrict__ Wn1, const float* __restrict__ Wn2,
                      bf16_t* __restrict__ W1p, bf16_t* __restrict__ W2p,
                      bf16_t* __restrict__ Wn1p, bf16_t* __restrict__ Wn2p) {
  int p = blockIdx.x * 256 + threadIdx.x;  // 0..16383
  const float* W; bf16_t* dst; int K, Nn, local, mode;
  if (p < 4096)       { W = We1; dst = W1p;  K = 128; Nn = 128; mode = 0; local = p; }
  else if (p < 8192)  { W = We2; dst = W2p;  K = 128; Nn = 128; mode = 1; local = p - 4096; }
  else if (p < 14336) { W = Wn1; dst = Wn1p; K = 192; Nn = 128; mode = 0; local = p - 8192; }
  else                { W = Wn2; dst = Wn2p; K = 128; Nn = 64;  mode = 1; local = p - 14336; }
  int lane = local & 63;
  int nnt = (Nn >> 4);
  int chunk = local >> 6;
  int nt = chunk % nnt;
  int s = chunk / nnt;
  int n = nt * 16 + (lane & 15);
  int kbase = s * 32 + ((lane >> 4) * 8);
  bf16x8 v;
#pragma unroll
  for (int j = 0; j < 8; ++j) {
    int kp = kbase + j;
    int region = kp / K;
    int kk = kp - region * K;
    float w = W[kk * Nn + n];
    bf16_t hi = f2b(w);
    v[j] = (mode == 1 && region == 1) ? f2b(w - b2f(hi)) : hi;
  }
  *(bf16x8*)(dst + (size_t)local * 8) = v;
}

// ---------------- Kernel A: x = nodes*m, sq, per-batch valid-index compaction ------
__global__ void __launch_bounds__(256) kprep(const float* __restrict__ nodes,
    const int* __restrict__ mask, float* __restrict__ x, float* __restrict__ sq,
    int* __restrict__ vlist, int* __restrict__ vcnt) {
  const int b = blockIdx.x, t = threadIdx.x, lane = t & 63, w = t >> 6;
  __shared__ int cnts[8];
  __shared__ int basep[8];
  unsigned long long bal[2]; int flag[2];
#pragma unroll
  for (int h = 0; h < 2; ++h) {
    const int n = h * 256 + t;
    const size_t ro = (size_t)(b * 512 + n) * 64;
    const int mk = mask[b * 512 + n];
    const float fm = (float)mk;
    float s = 0.f;
#pragma unroll
    for (int c = 0; c < 64; c += 4) {
      float4 v = *(const float4*)(nodes + ro + c);
      v.x *= fm; v.y *= fm; v.z *= fm; v.w *= fm;
      *(float4*)(x + ro + c) = v;
      s += v.x * v.x + v.y * v.y + v.z * v.z + v.w * v.w;
    }
    sq[b * 512 + n] = s;
    flag[h] = (mk != 0);
    bal[h] = __ballot(flag[h]);
    if (lane == 0) cnts[h * 4 + w] = __popcll(bal[h]);
  }
  __syncthreads();
  if (t == 0) {
    int a = 0;
    for (int c = 0; c < 8; ++c) { basep[c] = a; a += cnts[c]; }
    vcnt[b] = a;
  }
  __syncthreads();
#pragma unroll
  for (int h = 0; h < 2; ++h) {
    if (flag[h]) {
      const unsigned long long lt = (lane == 0) ? 0ull : (~0ull >> (64 - lane));
      const int pos = basep[h * 4 + w] + __popcll(bal[h] & lt);
      vlist[b * 512 + pos] = h * 256 + t;
    }
  }
}

// ---------------- Kernel B: distances over valid candidates + top-17 select --------
// Exactly mirrors jax.lax.top_k(-dist,K+1)[1:]: ascending (dist, index) keys over
// valid senders (masked senders have dist >= BIG, never in top-17), drop rank 0.
__global__ void __launch_bounds__(256) kknn(const float* __restrict__ x,
    const float* __restrict__ sq, const int* __restrict__ vlist,
    const int* __restrict__ vcnt, const int* __restrict__ mask,
    int* __restrict__ idxg) {
  const int wg = blockIdx.x, b = wg >> 3, rbase = (wg & 7) * 64;
  const int t = threadIdx.x, lane = t & 63, w = t >> 6;
  __shared__ float sqs[512];
  __shared__ int vls[512];
  for (int i = t; i < 512; i += 256) { sqs[i] = sq[b * 512 + i]; vls[i] = vlist[b * 512 + i]; }
  __syncthreads();
  const int nv = vcnt[b];
  const int jmax = (nv + 63) >> 6;
  const float* xb = x + (size_t)b * 512 * 64;
  for (int g = 0; g < 4; ++g) {
    const int n0 = rbase + w * 16 + g * 4;
    int mk[4];
#pragma unroll
    for (int i = 0; i < 4; ++i) mk[i] = mask[b * 512 + n0 + i];
    if (!(mk[0] | mk[1] | mk[2] | mk[3])) continue;
    int mj[8];
#pragma unroll
    for (int j = 0; j < 8; ++j) {
      const int c = j * 64 + lane;
      mj[j] = (j < jmax && c < nv) ? vls[c] : -1;
    }
    float accd[4][8];
#pragma unroll
    for (int i = 0; i < 4; ++i)
#pragma unroll
      for (int j = 0; j < 8; ++j) accd[i][j] = 0.f;
    for (int fc = 0; fc < 16; ++fc) {
      float4 xn4[4];
#pragma unroll
      for (int i = 0; i < 4; ++i)
        if (mk[i]) xn4[i] = *(const float4*)(xb + (size_t)(n0 + i) * 64 + fc * 4);
      for (int j = 0; j < jmax; ++j) {
        const int rowm = mj[j] < 0 ? 0 : mj[j];
        const float4 xm = *(const float4*)(xb + (size_t)rowm * 64 + fc * 4);
#pragma unroll
        for (int i = 0; i < 4; ++i)
          if (mk[i]) {
            float a = accd[i][j];
            a = fmaf(xn4[i].x, xm.x, a);
            a = fmaf(xn4[i].y, xm.y, a);
            a = fmaf(xn4[i].z, xm.z, a);
            a = fmaf(xn4[i].w, xm.w, a);
            accd[i][j] = a;
          }
      }
    }
    for (int i = 0; i < 4; ++i) {
      if (!mk[i]) continue;
      const int n = n0 + i;
      const float sqn = sqs[n];
      unsigned long long key[8];
#pragma unroll
      for (int j = 0; j < 8; ++j) {
        if (j < jmax && mj[j] >= 0) {
          const float d = fabsf(sqn + sqs[mj[j]] - 2.f * accd[i][j]);
          key[j] = (((unsigned long long)__float_as_uint(d)) << 32) | (unsigned)mj[j];
        } else key[j] = ~0ull;
      }
      int mywin = n;
      for (int ts = 0; ts < 17; ++ts) {
        unsigned long long lmin = ~0ull;
        for (int j = 0; j < jmax; ++j) lmin = key[j] < lmin ? key[j] : lmin;
        const unsigned long long wmin = wave_min_u64(lmin);
        if (ts > 0 && lane == ts - 1)
          mywin = (wmin == ~0ull) ? n : (int)(unsigned)(wmin & 0xffffffffull);
        for (int j = 0; j < jmax; ++j) if (key[j] == wmin) key[j] = ~0ull;
      }
      if (lane < 16) idxg[((size_t)b * 512 + n) * 16 + lane] = mywin;
    }
  }
}

// ---------------- Kernel C: edge MLP (wave = 2 nodes; M=16 edges per MFMA tile) ----
// L1: A' = [E_hi | E_lo] (K'=256, 8 slabs), B' = [W1_hi; W1_hi]  -> H1 (error: W1 rounding only)
// L2: A' = [H_hi | H_hi] (8 slabs),         B' = [W2_hi; W2_lo]  -> H2 (error: H rounding only)
__global__ void __launch_bounds__(256) kedge(const float* __restrict__ x,
    const int* __restrict__ mask, const int* __restrict__ idxg,
    const bf16_t* __restrict__ W1p, const bf16_t* __restrict__ W2p,
    const float* __restrict__ be1, const float* __restrict__ be2,
    float* __restrict__ pooled) {
  __shared__ __align__(16) bf16_t slab[4096];          // 8 KB
  __shared__ __align__(16) bf16_t hfrag[4][2][2048];   // 32 KB (lane-linear A-frags of H1)
  const int t = threadIdx.x, lane = t & 63, w = t >> 6;
  const int q = lane >> 4, e = lane & 15;
  const int gbase = blockIdx.x * 8 + w * 2;

  int gid[2]; bool act[2]; int sv[2]; float smv[2];
#pragma unroll
  for (int u = 0; u < 2; ++u) {
    gid[u] = gbase + u;
    act[u] = (mask[gid[u]] != 0);
    sv[u] = 0; smv[u] = 0.f;
    if (act[u]) {
      sv[u] = idxg[(size_t)gid[u] * 16 + e];
      const int bb = gid[u] >> 9;
      smv[u] = (float)mask[bb * 512 + sv[u]];
    }
  }

  f32x4 acc[2][8];
#pragma unroll
  for (int u = 0; u < 2; ++u)
#pragma unroll
    for (int nt = 0; nt < 8; ++nt) acc[u][nt] = zero4();

  // ---- Layer 1 ----
  for (int s = 0; s < 8; ++s) {
    __syncthreads();
    {
      const uint4* src = (const uint4*)(W1p + (size_t)s * 4096);
      uint4* dst = (uint4*)slab;
      for (int i = t; i < 512; i += 256) dst[i] = src[i];
    }
    __syncthreads();
    const bool wantlo = (s >= 4);
    const int sr = s & 3, half = sr >> 1, inner = sr & 1;
    const int col = inner * 32 + q * 8;
    bf16x8 af[2];
#pragma unroll
    for (int u = 0; u < 2; ++u) {
      if (act[u]) {
        const int bb = gid[u] >> 9;
        const int row = half ? (bb * 512 + sv[u]) : gid[u];
        af[u] = make_frag(x + (size_t)row * 64 + col, wantlo);
      }
    }
#pragma unroll
    for (int nt = 0; nt < 8; ++nt) {
      const bf16x8 bfv = *(const bf16x8*)(slab + (nt * 64 + lane) * 8);
#pragma unroll
      for (int u = 0; u < 2; ++u)
        if (act[u]) acc[u][nt] = __builtin_amdgcn_mfma_f32_16x16x32_bf16(af[u], bfv, acc[u][nt], 0, 0, 0);
    }
  }

  // ---- Epilogue 1: bias+relu -> bf16 hi -> lane-linear A-frag buffer ----
#pragma unroll
  for (int u = 0; u < 2; ++u) {
    if (act[u]) {
#pragma unroll
      for (int nt = 0; nt < 8; ++nt) {
        const int cc = nt * 16 + e;
        const float bv = be1[cc];
        const int base = ((cc >> 5) * 64 + (q * 4) + 16 * ((cc >> 3) & 3)) * 8 + (cc & 7);
#pragma unroll
        for (int r = 0; r < 4; ++r) {
          float h = fmaxf(acc[u][nt][r] + bv, 0.f);
          hfrag[w][u][base + r * 8] = f2b(h);
        }
      }
    }
  }

  // ---- Layer 2 ----
#pragma unroll
  for (int u = 0; u < 2; ++u)
#pragma unroll
    for (int nt = 0; nt < 8; ++nt) acc[u][nt] = zero4();

  for (int s = 0; s < 8; ++s) {
    __syncthreads();
    {
      const uint4* src = (const uint4*)(W2p + (size_t)s * 4096);
      uint4* dst = (uint4*)slab;
      for (int i = t; i < 512; i += 256) dst[i] = src[i];
    }
    __syncthreads();
    const int f = s & 3;
    bf16x8 af[2];
#pragma unroll
    for (int u = 0; u < 2; ++u)
      if (act[u]) af[u] = *(const bf16x8*)(&hfrag[w][u][(f * 64 + lane) * 8]);
#pragma unroll
    for (int nt = 0; nt < 8; ++nt) {
      const bf16x8 bfv = *(const bf16x8*)(slab + (nt * 64 + lane) * 8);
#pragma unroll
      for (int u = 0; u < 2; ++u)
        if (act[u]) acc[u][nt] = __builtin_amdgcn_mfma_f32_16x16x32_bf16(af[u], bfv, acc[u][nt], 0, 0, 0);
    }
  }

  // ---- Epilogue 2: bias+relu, mask senders, mean-pool over 16 edges ----
#pragma unroll
  for (int u = 0; u < 2; ++u) {
    if (act[u]) {
      float tc = (lane < 16) ? smv[u] : 0.f;
#pragma unroll
      for (int o = 1; o < 64; o <<= 1) tc += __shfl_xor(tc, o, 64);
      const float inv = 1.f / fmaxf(tc, 1.f);
      float sm[4];
#pragma unroll
      for (int r = 0; r < 4; ++r) sm[r] = __shfl(smv[u], q * 4 + r, 64);
#pragma unroll
      for (int nt = 0; nt < 8; ++nt) {
        const float bv = be2[nt * 16 + e];
        float part = 0.f;
#pragma unroll
        for (int r = 0; r < 4; ++r) {
          const float h = fmaxf(acc[u][nt][r] + bv, 0.f);
          part += h * sm[r];
        }
        part += __shfl_xor(part, 16, 64);
        part += __shfl_xor(part, 32, 64);
        if (lane < 16) pooled[(size_t)gid[u] * 128 + nt * 16 + lane] = part * inv;
      }
    } else {
      if (lane < 16) {
#pragma unroll
        for (int nt = 0; nt < 8; ++nt) pooled[(size_t)gid[u] * 128 + nt * 16 + lane] = 0.f;
      }
    }
  }
}

// ---------------- Kernel D: node MLP (wave = 2 tiles of 16 nodes) ------------------
// L1: A' = [NH_hi | NH_lo] (K'=384, 12 slabs), B' = [Wn1_hi; Wn1_hi]
// L2: A' = [T_hi | T_hi]   (8 slabs),          B' = [Wn2_hi; Wn2_lo]
__global__ void __launch_bounds__(256) knode(const float* __restrict__ x,
    const float* __restrict__ pooled, const int* __restrict__ mask,
    const bf16_t* __restrict__ Wn1p, const bf16_t* __restrict__ Wn2p,
    const float* __restrict__ bn1, const float* __restrict__ bn2,
    float* __restrict__ out) {
  __shared__ __align__(16) bf16_t slab[4096];          // 8 KB
  __shared__ __align__(16) bf16_t hfrag[4][2][2048];   // 32 KB
  const int t = threadIdx.x, lane = t & 63, w = t >> 6;
  const int q = lane >> 4, e = lane & 15;
  int nodebase[2];
#pragma unroll
  for (int u = 0; u < 2; ++u) nodebase[u] = (blockIdx.x * 8 + w * 2 + u) * 16;

  f32x4 acc[2][8];
#pragma unroll
  for (int u = 0; u < 2; ++u)
#pragma unroll
    for (int nt = 0; nt < 8; ++nt) acc[u][nt] = zero4();

  // ---- Layer 1 (12 slabs) ----
  for (int s = 0; s < 12; ++s) {
    __syncthreads();
    {
      const uint4* src = (const uint4*)(Wn1p + (size_t)s * 4096);
      uint4* dst = (uint4*)slab;
      for (int i = t; i < 512; i += 256) dst[i] = src[i];
    }
    __syncthreads();
    const bool wantlo = (s >= 6);
    const int sr = wantlo ? (s - 6) : s;
    const int col = sr * 32 + q * 8;  // [0,192); region uniform per s
    bf16x8 af[2];
#pragma unroll
    for (int u = 0; u < 2; ++u) {
      const int node = nodebase[u] + e;
      const float* p = (col < 64) ? (x + (size_t)node * 64 + col)
                                  : (pooled + (size_t)node * 128 + (col - 64));
      af[u] = make_frag(p, wantlo);
    }
#pragma unroll
    for (int nt = 0; nt < 8; ++nt) {
      const bf16x8 bfv = *(const bf16x8*)(slab + (nt * 64 + lane) * 8);
#pragma unroll
      for (int u = 0; u < 2; ++u)
        acc[u][nt] = __builtin_amdgcn_mfma_f32_16x16x32_bf16(af[u], bfv, acc[u][nt], 0, 0, 0);
    }
  }

  // ---- Epilogue 1 ----
#pragma unroll
  for (int u = 0; u < 2; ++u) {
#pragma unroll
    for (int nt = 0; nt < 8; ++nt) {
      const int cc = nt * 16 + e;
      const float bv = bn1[cc];
      const int base = ((cc >> 5) * 64 + (q * 4) + 16 * ((cc >> 3) & 3)) * 8 + (cc & 7);
#pragma unroll
      for (int r = 0; r < 4; ++r) {
        float h = fmaxf(acc[u][nt][r] + bv, 0.f);
        hfrag[w][u][base + r * 8] = f2b(h);
      }
    }
  }

  // ---- Layer 2 (8 slabs of 4 KB, N=64 -> 4 ntiles) ----
  f32x4 acc2[2][4];
#pragma unroll
  for (int u = 0; u < 2; ++u)
#pragma unroll
    for (int nt = 0; nt < 4; ++nt) acc2[u][nt] = zero4();

  for (int s = 0; s < 8; ++s) {
    __syncthreads();
    {
      const uint4* src = (const uint4*)(Wn2p + (size_t)s * 2048);
      uint4* dst = (uint4*)slab;
      for (int i = t; i < 256; i += 256) dst[i] = src[i];
    }
    __syncthreads();
    const int f = s & 3;
    bf16x8 af[2];
#pragma unroll
    for (int u = 0; u < 2; ++u)
      af[u] = *(const bf16x8*)(&hfrag[w][u][(f * 64 + lane) * 8]);
#pragma unroll
    for (int nt = 0; nt < 4; ++nt) {
      const bf16x8 bfv = *(const bf16x8*)(slab + (nt * 64 + lane) * 8);
#pragma unroll
      for (int u = 0; u < 2; ++u)
        acc2[u][nt] = __builtin_amdgcn_mfma_f32_16x16x32_bf16(af[u], bfv, acc2[u][nt], 0, 0, 0);
    }
  }

  // ---- Final: + bn2, * mask, store ----
#pragma unroll
  for (int u = 0; u < 2; ++u) {
    int mm[4];
#pragma unroll
    for (int r = 0; r < 4; ++r) mm[r] = mask[nodebase[u] + q * 4 + r];
#pragma unroll
    for (int nt = 0; nt < 4; ++nt) {
      const float bv = bn2[nt * 16 + e];
#pragma unroll
      for (int r = 0; r < 4; ++r) {
        const int node = nodebase[u] + q * 4 + r;
        out[(size_t)node * 64 + nt * 16 + e] = (acc2[u][nt][r] + bv) * (float)mm[r];
      }
    }
  }
}

// ---------------- Launch ----------------
extern "C" void kernel_launch(void* const* d_in, const int* in_sizes, int n_in,
                              void* d_out, int out_size, void* d_ws, size_t ws_size,
                              hipStream_t stream) {
  const float* nodes = (const float*)d_in[0];
  const int*   mask  = (const int*)d_in[1];
  const float* We1   = (const float*)d_in[2];
  const float* be1   = (const float*)d_in[3];
  const float* We2   = (const float*)d_in[4];
  const float* be2   = (const float*)d_in[5];
  const float* Wn1   = (const float*)d_in[6];
  const float* bn1   = (const float*)d_in[7];
  const float* Wn2   = (const float*)d_in[8];
  const float* bn2   = (const float*)d_in[9];
  float* out = (float*)d_out;

  char* p = (char*)d_ws;
  auto alloc = [&](size_t bytes) -> char* {
    char* r = p;
    p += (bytes + 255) & ~(size_t)255;
    return r;
  };
  float*  x      = (float*)alloc((size_t)32768 * 64 * 4);
  float*  sq     = (float*)alloc((size_t)32768 * 4);
  int*    vlist  = (int*)alloc((size_t)32768 * 4);
  int*    vcnt   = (int*)alloc((size_t)64 * 4);
  int*    idxg   = (int*)alloc((size_t)32768 * 16 * 4);
  float*  pooled = (float*)alloc((size_t)32768 * 128 * 4);
  bf16_t* W1p    = (bf16_t*)alloc((size_t)8 * 8 * 64 * 8 * 2);
  bf16_t* W2p    = (bf16_t*)alloc((size_t)8 * 8 * 64 * 8 * 2);
  bf16_t* Wn1p   = (bf16_t*)alloc((size_t)12 * 8 * 64 * 8 * 2);
  bf16_t* Wn2p   = (bf16_t*)alloc((size_t)8 * 4 * 64 * 8 * 2);
  if ((size_t)(p - (char*)d_ws) > ws_size) return;  // workspace too small -> loud failure

  kpack<<<64, 256, 0, stream>>>(We1, We2, Wn1, Wn2, W1p, W2p, Wn1p, Wn2p);
  kprep<<<64, 256, 0, stream>>>(nodes, mask, x, sq, vlist, vcnt);
  kknn<<<512, 256, 0, stream>>>(x, sq, vlist, vcnt, mask, idxg);
  kedge<<<4096, 256, 0, stream>>>(x, mask, idxg, W1p, W2p, be1, be2, pooled);
  knode<<<256, 256, 0, stream>>>(x, pooled, mask, Wn1p, Wn2p, bn1, bn2, out);
}

// Round 2
// 547.512 us; speedup vs baseline: 1.0681x; 1.0681x over previous
//
#include <hip/hip_runtime.h>

#define DI __device__ __forceinline__

typedef __bf16 bf16_t;
typedef __bf16 bf16x8 __attribute__((ext_vector_type(8)));
typedef float f32x4 __attribute__((ext_vector_type(4)));

// Problem constants
// B=64, N=512, F=64, H=128, FO=64, K=16
// Edge MLP: E(16x128) @ We1(128x128) -> relu -> @ We2(128x128) -> relu -> mean -> pooled(128)
// Node MLP: [x|pooled](192) @ Wn1(192x128) -> relu -> @ Wn2(128x64) -> out, * mask

DI bf16_t f2b(float f) {
  unsigned u = __float_as_uint(f);
  unsigned r = (u + 0x7fffu + ((u >> 16) & 1u)) >> 16;
  return __builtin_bit_cast(bf16_t, (unsigned short)r);
}
DI float b2f(bf16_t h) {
  return __uint_as_float(((unsigned)__builtin_bit_cast(unsigned short, h)) << 16);
}
DI f32x4 zero4() { f32x4 z = {0.f, 0.f, 0.f, 0.f}; return z; }

DI bf16x8 make_frag(const float* p, bool wantlo) {
  float4 v0 = *(const float4*)p;
  float4 v1 = *(const float4*)(p + 4);
  float vv[8] = {v0.x, v0.y, v0.z, v0.w, v1.x, v1.y, v1.z, v1.w};
  bf16x8 a;
#pragma unroll
  for (int j = 0; j < 8; ++j) {
    bf16_t hi = f2b(vv[j]);
    a[j] = wantlo ? f2b(vv[j] - b2f(hi)) : hi;
  }
  return a;
}

DI unsigned long long wave_min_u64(unsigned long long v) {
#pragma unroll
  for (int o = 1; o < 64; o <<= 1) {
    unsigned lo = (unsigned)(v & 0xffffffffull);
    unsigned hi = (unsigned)(v >> 32);
    unsigned olo = __shfl_xor(lo, o, 64);
    unsigned ohi = __shfl_xor(hi, o, 64);
    unsigned long long ov = (((unsigned long long)ohi) << 32) | olo;
    v = ov < v ? ov : v;
  }
  return v;
}

// ---------------- Kernel P: pack weights into split-bf16 MFMA B-fragment layout ----
__global__ void kpack(const float* __restrict__ We1, const float* __restrict__ We2,
                      const float* __restrict__ Wn1, const float* __restrict__ Wn2,
                      bf16_t* __restrict__ W1p, bf16_t* __restrict__ W2p,
                      bf16_t* __restrict__ Wn1p, bf16_t* __restrict__ Wn2p) {
  int p = blockIdx.x * 256 + threadIdx.x;  // 0..16383
  const float* W; bf16_t* dst; int K, Nn, local, mode;
  if (p < 4096)       { W = We1; dst = W1p;  K = 128; Nn = 128; mode = 0; local = p; }
  else if (p < 8192)  { W = We2; dst = W2p;  K = 128; Nn = 128; mode = 1; local = p - 4096; }
  else if (p < 14336) { W = Wn1; dst = Wn1p; K = 192; Nn = 128; mode = 0; local = p - 8192; }
  else                { W = Wn2; dst = Wn2p; K = 128; Nn = 64;  mode = 1; local = p - 14336; }
  int lane = local & 63;
  int nnt = (Nn >> 4);
  int chunk = local >> 6;
  int nt = chunk % nnt;
  int s = chunk / nnt;
  int n = nt * 16 + (lane & 15);
  int kbase = s * 32 + ((lane >> 4) * 8);
  bf16x8 v;
#pragma unroll
  for (int j = 0; j < 8; ++j) {
    int kp = kbase + j;
    int region = kp / K;
    int kk = kp - region * K;
    float w = W[kk * Nn + n];
    bf16_t hi = f2b(w);
    v[j] = (mode == 1 && region == 1) ? f2b(w - b2f(hi)) : hi;
  }
  *(bf16x8*)(dst + (size_t)local * 8) = v;
}

// ---------------- Kernel A: x = nodes*m, sq, per-batch valid-index compaction ------
__global__ void __launch_bounds__(256) kprep(const float* __restrict__ nodes,
    const int* __restrict__ mask, float* __restrict__ x, float* __restrict__ sq,
    int* __restrict__ vlist, int* __restrict__ vcnt) {
  const int b = blockIdx.x, t = threadIdx.x, lane = t & 63, w = t >> 6;
  __shared__ int cnts[8];
  __shared__ int basep[8];
  unsigned long long bal[2]; int flag[2];
#pragma unroll
  for (int h = 0; h < 2; ++h) {
    const int n = h * 256 + t;
    const size_t ro = (size_t)(b * 512 + n) * 64;
    const int mk = mask[b * 512 + n];
    const float fm = (float)mk;
    float s = 0.f;
#pragma unroll
    for (int c = 0; c < 64; c += 4) {
      float4 v = *(const float4*)(nodes + ro + c);
      v.x *= fm; v.y *= fm; v.z *= fm; v.w *= fm;
      *(float4*)(x + ro + c) = v;
      s += v.x * v.x + v.y * v.y + v.z * v.z + v.w * v.w;
    }
    sq[b * 512 + n] = s;
    flag[h] = (mk != 0);
    bal[h] = __ballot(flag[h]);
    if (lane == 0) cnts[h * 4 + w] = __popcll(bal[h]);
  }
  __syncthreads();
  if (t == 0) {
    int a = 0;
    for (int c = 0; c < 8; ++c) { basep[c] = a; a += cnts[c]; }
    vcnt[b] = a;
  }
  __syncthreads();
#pragma unroll
  for (int h = 0; h < 2; ++h) {
    if (flag[h]) {
      const unsigned long long lt = (lane == 0) ? 0ull : (~0ull >> (64 - lane));
      const int pos = basep[h * 4 + w] + __popcll(bal[h] & lt);
      vlist[b * 512 + pos] = h * 256 + t;
    }
  }
}

// ---------------- Kernel B: distances + top-17, LDS-staged compacted candidates ----
// Grid: 64 batches x 16 tiles of 32 receivers. Wave = 8 receivers (2 groups of 4).
// Candidates staged per chunk of 128 compacted rows into LDS (stride 68 floats ->
// ds_read_b128 at the 8-clk bandwidth floor, uniform bank coverage).
// Selection mirrors jax.lax.top_k(-dist,K+1)[1:] exactly: ascending (dist,index)
// u64 keys over valid senders, drop rank 0 (self).
__global__ void __launch_bounds__(256) kknn(const float* __restrict__ x,
    const float* __restrict__ sq, const int* __restrict__ vlist,
    const int* __restrict__ vcnt, const int* __restrict__ mask,
    int* __restrict__ idxg) {
  const int wg = blockIdx.x, b = wg >> 4, rbase = (wg & 15) * 32;
  const int t = threadIdx.x, lane = t & 63, w = t >> 6;
  __shared__ float sqs[512];
  __shared__ int vls[512];
  __shared__ __align__(16) float xc[128 * 68];  // 34 KB, row stride 68 floats
  for (int i = t; i < 512; i += 256) { sqs[i] = sq[b * 512 + i]; vls[i] = vlist[b * 512 + i]; }
  __syncthreads();
  const int nv = vcnt[b];
  const int nchunk = (nv + 127) >> 7;
  const int jmax = (nv + 63) >> 6;
  const float* xb = x + (size_t)b * 512 * 64;

  int mk[2][4];
  int n0[2];
#pragma unroll
  for (int g = 0; g < 2; ++g) {
    n0[g] = rbase + w * 8 + g * 4;
#pragma unroll
    for (int i = 0; i < 4; ++i) mk[g][i] = mask[b * 512 + n0[g] + i];
  }

  float accd[2][4][8];
#pragma unroll
  for (int g = 0; g < 2; ++g)
#pragma unroll
    for (int i = 0; i < 4; ++i)
#pragma unroll
      for (int j = 0; j < 8; ++j) accd[g][i][j] = 0.f;

  for (int cb = 0; cb < nchunk; ++cb) {
    __syncthreads();
    // stage chunk: 128 compacted rows, 16 threads per row (float4 each)
    {
      const int f4 = (t & 15) * 4;
      const int cl0 = t >> 4;  // 0..15
#pragma unroll
      for (int p = 0; p < 8; ++p) {
        const int cl = cl0 + p * 16;
        const int c = cb * 128 + cl;
        if (c < nv) {
          const int row = vls[c];
          *(float4*)(xc + cl * 68 + f4) = *(const float4*)(xb + (size_t)row * 64 + f4);
        }
      }
    }
    __syncthreads();
    const int jc = min(2, jmax - cb * 2);
#pragma unroll
    for (int g = 0; g < 2; ++g) {
      if (!(mk[g][0] | mk[g][1] | mk[g][2] | mk[g][3])) continue;
      for (int fc = 0; fc < 16; ++fc) {
        float4 xn4[4];
#pragma unroll
        for (int i = 0; i < 4; ++i)
          xn4[i] = *(const float4*)(xb + (size_t)(n0[g] + i) * 64 + fc * 4);
        for (int j2 = 0; j2 < jc; ++j2) {
          const float4 xm = *(const float4*)(xc + (j2 * 64 + lane) * 68 + fc * 4);
#pragma unroll
          for (int i = 0; i < 4; ++i) {
            float a = accd[g][i][cb * 2 + j2];
            a = fmaf(xn4[i].x, xm.x, a);
            a = fmaf(xn4[i].y, xm.y, a);
            a = fmaf(xn4[i].z, xm.z, a);
            a = fmaf(xn4[i].w, xm.w, a);
            accd[g][i][cb * 2 + j2] = a;
          }
        }
      }
    }
  }

  // selection
#pragma unroll
  for (int g = 0; g < 2; ++g) {
    for (int i = 0; i < 4; ++i) {
      if (!mk[g][i]) continue;
      const int n = n0[g] + i;
      const float sqn = sqs[n];
      unsigned long long key[8];
#pragma unroll
      for (int j = 0; j < 8; ++j) {
        const int c = j * 64 + lane;
        if (j < jmax && c < nv) {
          const int mj = vls[c];
          const float d = fabsf(sqn + sqs[mj] - 2.f * accd[g][i][j]);
          key[j] = (((unsigned long long)__float_as_uint(d)) << 32) | (unsigned)mj;
        } else key[j] = ~0ull;
      }
      int mywin = n;
      for (int ts = 0; ts < 17; ++ts) {
        unsigned long long lmin = ~0ull;
        for (int j = 0; j < jmax; ++j) lmin = key[j] < lmin ? key[j] : lmin;
        const unsigned long long wmin = wave_min_u64(lmin);
        if (ts > 0 && lane == ts - 1)
          mywin = (wmin == ~0ull) ? n : (int)(unsigned)(wmin & 0xffffffffull);
        for (int j = 0; j < jmax; ++j) if (key[j] == wmin) key[j] = ~0ull;
      }
      if (lane < 16) idxg[((size_t)b * 512 + n) * 16 + lane] = mywin;
    }
  }
}

// ---------------- Kernel C: edge MLP (wave = 2 nodes; M=16 edges per MFMA tile) ----
// L1: A' = [E_hi | E_lo] (K'=256, 8 slabs), B' = [W1_hi; W1_hi]  -> H1 (error: W1 rounding only)
// L2: A' = [H_hi | H_hi] (8 slabs),         B' = [W2_hi; W2_lo]  -> H2 (error: H rounding only)
__global__ void __launch_bounds__(256) kedge(const float* __restrict__ x,
    const int* __restrict__ mask, const int* __restrict__ idxg,
    const bf16_t* __restrict__ W1p, const bf16_t* __restrict__ W2p,
    const float* __restrict__ be1, const float* __restrict__ be2,
    float* __restrict__ pooled) {
  __shared__ __align__(16) bf16_t slab[4096];          // 8 KB
  __shared__ __align__(16) bf16_t hfrag[4][2][2048];   // 32 KB (lane-linear A-frags of H1)
  const int t = threadIdx.x, lane = t & 63, w = t >> 6;
  const int q = lane >> 4, e = lane & 15;
  const int gbase = blockIdx.x * 8 + w * 2;

  int gid[2]; bool act[2]; int sv[2]; float smv[2];
#pragma unroll
  for (int u = 0; u < 2; ++u) {
    gid[u] = gbase + u;
    act[u] = (mask[gid[u]] != 0);
    sv[u] = 0; smv[u] = 0.f;
    if (act[u]) {
      sv[u] = idxg[(size_t)gid[u] * 16 + e];
      const int bb = gid[u] >> 9;
      smv[u] = (float)mask[bb * 512 + sv[u]];
    }
  }

  f32x4 acc[2][8];
#pragma unroll
  for (int u = 0; u < 2; ++u)
#pragma unroll
    for (int nt = 0; nt < 8; ++nt) acc[u][nt] = zero4();

  // ---- Layer 1 ----
  for (int s = 0; s < 8; ++s) {
    __syncthreads();
    {
      const uint4* src = (const uint4*)(W1p + (size_t)s * 4096);
      uint4* dst = (uint4*)slab;
      for (int i = t; i < 512; i += 256) dst[i] = src[i];
    }
    __syncthreads();
    const bool wantlo = (s >= 4);
    const int sr = s & 3, half = sr >> 1, inner = sr & 1;
    const int col = inner * 32 + q * 8;
    bf16x8 af[2];
#pragma unroll
    for (int u = 0; u < 2; ++u) {
      if (act[u]) {
        const int bb = gid[u] >> 9;
        const int row = half ? (bb * 512 + sv[u]) : gid[u];
        af[u] = make_frag(x + (size_t)row * 64 + col, wantlo);
      }
    }
#pragma unroll
    for (int nt = 0; nt < 8; ++nt) {
      const bf16x8 bfv = *(const bf16x8*)(slab + (nt * 64 + lane) * 8);
#pragma unroll
      for (int u = 0; u < 2; ++u)
        if (act[u]) acc[u][nt] = __builtin_amdgcn_mfma_f32_16x16x32_bf16(af[u], bfv, acc[u][nt], 0, 0, 0);
    }
  }

  // ---- Epilogue 1: bias+relu -> bf16 hi -> lane-linear A-frag buffer ----
#pragma unroll
  for (int u = 0; u < 2; ++u) {
    if (act[u]) {
#pragma unroll
      for (int nt = 0; nt < 8; ++nt) {
        const int cc = nt * 16 + e;
        const float bv = be1[cc];
        const int base = ((cc >> 5) * 64 + (q * 4) + 16 * ((cc >> 3) & 3)) * 8 + (cc & 7);
#pragma unroll
        for (int r = 0; r < 4; ++r) {
          float h = fmaxf(acc[u][nt][r] + bv, 0.f);
          hfrag[w][u][base + r * 8] = f2b(h);
        }
      }
    }
  }

  // ---- Layer 2 ----
#pragma unroll
  for (int u = 0; u < 2; ++u)
#pragma unroll
    for (int nt = 0; nt < 8; ++nt) acc[u][nt] = zero4();

  for (int s = 0; s < 8; ++s) {
    __syncthreads();
    {
      const uint4* src = (const uint4*)(W2p + (size_t)s * 4096);
      uint4* dst = (uint4*)slab;
      for (int i = t; i < 512; i += 256) dst[i] = src[i];
    }
    __syncthreads();
    const int f = s & 3;
    bf16x8 af[2];
#pragma unroll
    for (int u = 0; u < 2; ++u)
      if (act[u]) af[u] = *(const bf16x8*)(&hfrag[w][u][(f * 64 + lane) * 8]);
#pragma unroll
    for (int nt = 0; nt < 8; ++nt) {
      const bf16x8 bfv = *(const bf16x8*)(slab + (nt * 64 + lane) * 8);
#pragma unroll
      for (int u = 0; u < 2; ++u)
        if (act[u]) acc[u][nt] = __builtin_amdgcn_mfma_f32_16x16x32_bf16(af[u], bfv, acc[u][nt], 0, 0, 0);
    }
  }

  // ---- Epilogue 2: bias+relu, mask senders, mean-pool over 16 edges ----
#pragma unroll
  for (int u = 0; u < 2; ++u) {
    if (act[u]) {
      float tc = (lane < 16) ? smv[u] : 0.f;
#pragma unroll
      for (int o = 1; o < 64; o <<= 1) tc += __shfl_xor(tc, o, 64);
      const float inv = 1.f / fmaxf(tc, 1.f);
      float sm[4];
#pragma unroll
      for (int r = 0; r < 4; ++r) sm[r] = __shfl(smv[u], q * 4 + r, 64);
#pragma unroll
      for (int nt = 0; nt < 8; ++nt) {
        const float bv = be2[nt * 16 + e];
        float part = 0.f;
#pragma unroll
        for (int r = 0; r < 4; ++r) {
          const float h = fmaxf(acc[u][nt][r] + bv, 0.f);
          part += h * sm[r];
        }
        part += __shfl_xor(part, 16, 64);
        part += __shfl_xor(part, 32, 64);
        if (lane < 16) pooled[(size_t)gid[u] * 128 + nt * 16 + lane] = part * inv;
      }
    } else {
      if (lane < 16) {
#pragma unroll
        for (int nt = 0; nt < 8; ++nt) pooled[(size_t)gid[u] * 128 + nt * 16 + lane] = 0.f;
      }
    }
  }
}

// ---------------- Kernel D: node MLP (wave = 2 tiles of 16 nodes) ------------------
// L1: A' = [NH_hi | NH_lo] (K'=384, 12 slabs), B' = [Wn1_hi; Wn1_hi]
// L2: A' = [T_hi | T_hi]   (8 slabs),          B' = [Wn2_hi; Wn2_lo]
__global__ void __launch_bounds__(256) knode(const float* __restrict__ x,
    const float* __restrict__ pooled, const int* __restrict__ mask,
    const bf16_t* __restrict__ Wn1p, const bf16_t* __restrict__ Wn2p,
    const float* __restrict__ bn1, const float* __restrict__ bn2,
    float* __restrict__ out) {
  __shared__ __align__(16) bf16_t slab[4096];          // 8 KB
  __shared__ __align__(16) bf16_t hfrag[4][2][2048];   // 32 KB
  const int t = threadIdx.x, lane = t & 63, w = t >> 6;
  const int q = lane >> 4, e = lane & 15;
  int nodebase[2];
#pragma unroll
  for (int u = 0; u < 2; ++u) nodebase[u] = (blockIdx.x * 8 + w * 2 + u) * 16;

  f32x4 acc[2][8];
#pragma unroll
  for (int u = 0; u < 2; ++u)
#pragma unroll
    for (int nt = 0; nt < 8; ++nt) acc[u][nt] = zero4();

  // ---- Layer 1 (12 slabs) ----
  for (int s = 0; s < 12; ++s) {
    __syncthreads();
    {
      const uint4* src = (const uint4*)(Wn1p + (size_t)s * 4096);
      uint4* dst = (uint4*)slab;
      for (int i = t; i < 512; i += 256) dst[i] = src[i];
    }
    __syncthreads();
    const bool wantlo = (s >= 6);
    const int sr = wantlo ? (s - 6) : s;
    const int col = sr * 32 + q * 8;  // [0,192); region uniform per s
    bf16x8 af[2];
#pragma unroll
    for (int u = 0; u < 2; ++u) {
      const int node = nodebase[u] + e;
      const float* p = (col < 64) ? (x + (size_t)node * 64 + col)
                                  : (pooled + (size_t)node * 128 + (col - 64));
      af[u] = make_frag(p, wantlo);
    }
#pragma unroll
    for (int nt = 0; nt < 8; ++nt) {
      const bf16x8 bfv = *(const bf16x8*)(slab + (nt * 64 + lane) * 8);
#pragma unroll
      for (int u = 0; u < 2; ++u)
        acc[u][nt] = __builtin_amdgcn_mfma_f32_16x16x32_bf16(af[u], bfv, acc[u][nt], 0, 0, 0);
    }
  }

  // ---- Epilogue 1 ----
#pragma unroll
  for (int u = 0; u < 2; ++u) {
#pragma unroll
    for (int nt = 0; nt < 8; ++nt) {
      const int cc = nt * 16 + e;
      const float bv = bn1[cc];
      const int base = ((cc >> 5) * 64 + (q * 4) + 16 * ((cc >> 3) & 3)) * 8 + (cc & 7);
#pragma unroll
      for (int r = 0; r < 4; ++r) {
        float h = fmaxf(acc[u][nt][r] + bv, 0.f);
        hfrag[w][u][base + r * 8] = f2b(h);
      }
    }
  }

  // ---- Layer 2 (8 slabs of 4 KB, N=64 -> 4 ntiles) ----
  f32x4 acc2[2][4];
#pragma unroll
  for (int u = 0; u < 2; ++u)
#pragma unroll
    for (int nt = 0; nt < 4; ++nt) acc2[u][nt] = zero4();

  for (int s = 0; s < 8; ++s) {
    __syncthreads();
    {
      const uint4* src = (const uint4*)(Wn2p + (size_t)s * 2048);
      uint4* dst = (uint4*)slab;
      for (int i = t; i < 256; i += 256) dst[i] = src[i];
    }
    __syncthreads();
    const int f = s & 3;
    bf16x8 af[2];
#pragma unroll
    for (int u = 0; u < 2; ++u)
      af[u] = *(const bf16x8*)(&hfrag[w][u][(f * 64 + lane) * 8]);
#pragma unroll
    for (int nt = 0; nt < 4; ++nt) {
      const bf16x8 bfv = *(const bf16x8*)(slab + (nt * 64 + lane) * 8);
#pragma unroll
      for (int u = 0; u < 2; ++u)
        acc2[u][nt] = __builtin_amdgcn_mfma_f32_16x16x32_bf16(af[u], bfv, acc2[u][nt], 0, 0, 0);
    }
  }

  // ---- Final: + bn2, * mask, store ----
#pragma unroll
  for (int u = 0; u < 2; ++u) {
    int mm[4];
#pragma unroll
    for (int r = 0; r < 4; ++r) mm[r] = mask[nodebase[u] + q * 4 + r];
#pragma unroll
    for (int nt = 0; nt < 4; ++nt) {
      const float bv = bn2[nt * 16 + e];
#pragma unroll
      for (int r = 0; r < 4; ++r) {
        const int node = nodebase[u] + q * 4 + r;
        out[(size_t)node * 64 + nt * 16 + e] = (acc2[u][nt][r] + bv) * (float)mm[r];
      }
    }
  }
}

// ---------------- Launch ----------------
extern "C" void kernel_launch(void* const* d_in, const int* in_sizes, int n_in,
                              void* d_out, int out_size, void* d_ws, size_t ws_size,
                              hipStream_t stream) {
  const float* nodes = (const float*)d_in[0];
  const int*   mask  = (const int*)d_in[1];
  const float* We1   = (const float*)d_in[2];
  const float* be1   = (const float*)d_in[3];
  const float* We2   = (const float*)d_in[4];
  const float* be2   = (const float*)d_in[5];
  const float* Wn1   = (const float*)d_in[6];
  const float* bn1   = (const float*)d_in[7];
  const float* Wn2   = (const float*)d_in[8];
  const float* bn2   = (const float*)d_in[9];
  float* out = (float*)d_out;

  char* p = (char*)d_ws;
  auto alloc = [&](size_t bytes) -> char* {
    char* r = p;
    p += (bytes + 255) & ~(size_t)255;
    return r;
  };
  float*  x      = (float*)alloc((size_t)32768 * 64 * 4);
  float*  sq     = (float*)alloc((size_t)32768 * 4);
  int*    vlist  = (int*)alloc((size_t)32768 * 4);
  int*    vcnt   = (int*)alloc((size_t)64 * 4);
  int*    idxg   = (int*)alloc((size_t)32768 * 16 * 4);
  float*  pooled = (float*)alloc((size_t)32768 * 128 * 4);
  bf16_t* W1p    = (bf16_t*)alloc((size_t)8 * 8 * 64 * 8 * 2);
  bf16_t* W2p    = (bf16_t*)alloc((size_t)8 * 8 * 64 * 8 * 2);
  bf16_t* Wn1p   = (bf16_t*)alloc((size_t)12 * 8 * 64 * 8 * 2);
  bf16_t* Wn2p   = (bf16_t*)alloc((size_t)8 * 4 * 64 * 8 * 2);
  if ((size_t)(p - (char*)d_ws) > ws_size) return;  // workspace too small -> loud failure

  kpack<<<64, 256, 0, stream>>>(We1, We2, Wn1, Wn2, W1p, W2p, Wn1p, Wn2p);
  kprep<<<64, 256, 0, stream>>>(nodes, mask, x, sq, vlist, vcnt);
  kknn<<<1024, 256, 0, stream>>>(x, sq, vlist, vcnt, mask, idxg);
  kedge<<<4096, 256, 0, stream>>>(x, mask, idxg, W1p, W2p, be1, be2, pooled);
  knode<<<256, 256, 0, stream>>>(x, pooled, mask, Wn1p, Wn2p, bn1, bn2, out);
}

// Round 3
// 414.944 us; speedup vs baseline: 1.4093x; 1.3195x over previous
//
#include <hip/hip_runtime.h>

#define DI __device__ __forceinline__

typedef __bf16 bf16_t;
typedef __bf16 bf16x4 __attribute__((ext_vector_type(4)));
typedef __bf16 bf16x8 __attribute__((ext_vector_type(8)));
typedef float f32x4 __attribute__((ext_vector_type(4)));

// Problem constants
// B=64, N=512, F=64, H=128, FO=64, K=16
// Edge MLP: E(16x128) @ We1(128x128) -> relu -> @ We2(128x128) -> relu -> mean -> pooled(128)
// Node MLP: [x|pooled](192) @ Wn1(192x128) -> relu -> @ Wn2(128x64) -> out, * mask

DI bf16_t f2b(float f) {
  unsigned u = __float_as_uint(f);
  unsigned r = (u + 0x7fffu + ((u >> 16) & 1u)) >> 16;
  return __builtin_bit_cast(bf16_t, (unsigned short)r);
}
DI float b2f(bf16_t h) {
  return __uint_as_float(((unsigned)__builtin_bit_cast(unsigned short, h)) << 16);
}
DI f32x4 zero4() { f32x4 z = {0.f, 0.f, 0.f, 0.f}; return z; }

DI bf16x8 make_frag(const float* p, bool wantlo) {
  float4 v0 = *(const float4*)p;
  float4 v1 = *(const float4*)(p + 4);
  float vv[8] = {v0.x, v0.y, v0.z, v0.w, v1.x, v1.y, v1.z, v1.w};
  bf16x8 a;
#pragma unroll
  for (int j = 0; j < 8; ++j) {
    bf16_t hi = f2b(vv[j]);
    a[j] = wantlo ? f2b(vv[j] - b2f(hi)) : hi;
  }
  return a;
}

DI unsigned long long wave_min_u64(unsigned long long v) {
#pragma unroll
  for (int o = 1; o < 64; o <<= 1) {
    unsigned lo = (unsigned)(v & 0xffffffffull);
    unsigned hi = (unsigned)(v >> 32);
    unsigned olo = __shfl_xor(lo, o, 64);
    unsigned ohi = __shfl_xor(hi, o, 64);
    unsigned long long ov = (((unsigned long long)ohi) << 32) | olo;
    v = ov < v ? ov : v;
  }
  return v;
}

// ---------------- Kernel P: pack weights into split-bf16 MFMA B-fragment layout ----
__global__ void kpack(const float* __restrict__ We1, const float* __restrict__ We2,
                      const float* __restrict__ Wn1, const float* __restrict__ Wn2,
                      bf16_t* __restrict__ W1p, bf16_t* __restrict__ W2p,
                      bf16_t* __restrict__ Wn1p, bf16_t* __restrict__ Wn2p) {
  int p = blockIdx.x * 256 + threadIdx.x;  // 0..16383
  const float* W; bf16_t* dst; int K, Nn, local, mode;
  if (p < 4096)       { W = We1; dst = W1p;  K = 128; Nn = 128; mode = 0; local = p; }
  else if (p < 8192)  { W = We2; dst = W2p;  K = 128; Nn = 128; mode = 1; local = p - 4096; }
  else if (p < 14336) { W = Wn1; dst = Wn1p; K = 192; Nn = 128; mode = 0; local = p - 8192; }
  else                { W = Wn2; dst = Wn2p; K = 128; Nn = 64;  mode = 1; local = p - 14336; }
  int lane = local & 63;
  int nnt = (Nn >> 4);
  int chunk = local >> 6;
  int nt = chunk % nnt;
  int s = chunk / nnt;
  int n = nt * 16 + (lane & 15);
  int kbase = s * 32 + ((lane >> 4) * 8);
  bf16x8 v;
#pragma unroll
  for (int j = 0; j < 8; ++j) {
    int kp = kbase + j;
    int region = kp / K;
    int kk = kp - region * K;
    float w = W[kk * Nn + n];
    bf16_t hi = f2b(w);
    v[j] = (mode == 1 && region == 1) ? f2b(w - b2f(hi)) : hi;
  }
  *(bf16x8*)(dst + (size_t)local * 8) = v;
}

// ---------------- Kernel A: x, xhi/xlo planes, sq, per-batch compaction ------------
__global__ void __launch_bounds__(256) kprep(const float* __restrict__ nodes,
    const int* __restrict__ mask, float* __restrict__ x,
    bf16_t* __restrict__ xhi, bf16_t* __restrict__ xlo,
    float* __restrict__ sq, int* __restrict__ vlist, int* __restrict__ vcnt) {
  const int b = blockIdx.x, t = threadIdx.x, lane = t & 63, w = t >> 6;
  __shared__ int cnts[8];
  __shared__ int basep[8];
  unsigned long long bal[2]; int flag[2];
#pragma unroll
  for (int h = 0; h < 2; ++h) {
    const int n = h * 256 + t;
    const size_t ro = (size_t)(b * 512 + n) * 64;
    const int mk = mask[b * 512 + n];
    const float fm = (float)mk;
    float s = 0.f;
#pragma unroll
    for (int c = 0; c < 64; c += 4) {
      float4 v = *(const float4*)(nodes + ro + c);
      v.x *= fm; v.y *= fm; v.z *= fm; v.w *= fm;
      *(float4*)(x + ro + c) = v;
      float vv[4] = {v.x, v.y, v.z, v.w};
      bf16x4 hh, ll;
#pragma unroll
      for (int k = 0; k < 4; ++k) {
        bf16_t hi = f2b(vv[k]);
        hh[k] = hi;
        ll[k] = f2b(vv[k] - b2f(hi));
      }
      *(bf16x4*)(xhi + ro + c) = hh;
      *(bf16x4*)(xlo + ro + c) = ll;
      s += v.x * v.x + v.y * v.y + v.z * v.z + v.w * v.w;
    }
    sq[b * 512 + n] = s;
    flag[h] = (mk != 0);
    bal[h] = __ballot(flag[h]);
    if (lane == 0) cnts[h * 4 + w] = __popcll(bal[h]);
  }
  __syncthreads();
  if (t == 0) {
    int a = 0;
    for (int c = 0; c < 8; ++c) { basep[c] = a; a += cnts[c]; }
    vcnt[b] = a;
  }
  __syncthreads();
#pragma unroll
  for (int h = 0; h < 2; ++h) {
    if (flag[h]) {
      const unsigned long long lt = (lane == 0) ? 0ull : (~0ull >> (64 - lane));
      const int pos = basep[h * 4 + w] + __popcll(bal[h] & lt);
      vlist[b * 512 + pos] = h * 256 + t;
    }
  }
}

// ---------------- Kernel B: distances + top-17, compacted receivers & senders ------
// Grid: 64 batches x 16 tiles of 32 COMPACTED receiver slots; blocks past vcnt exit.
// All hot arrays statically indexed (uniform guards, full unroll) -> registers.
// Selection mirrors jax.lax.top_k(-dist,K+1)[1:] exactly over valid senders.
__global__ void __launch_bounds__(256) kknn(const float* __restrict__ x,
    const float* __restrict__ sq, const int* __restrict__ vlist,
    const int* __restrict__ vcnt, int* __restrict__ idxg) {
  const int wg = blockIdx.x, b = wg >> 4, rbase = (wg & 15) * 32;
  const int nv = vcnt[b];
  if (rbase >= nv) return;  // block-uniform, before any barrier
  const int t = threadIdx.x, lane = t & 63, w = t >> 6;
  __shared__ float sqs[512];
  __shared__ int vls[512];
  __shared__ __align__(16) float xc[128 * 68];  // 34 KB, row stride 68 floats
  for (int i = t; i < 512; i += 256) { sqs[i] = sq[b * 512 + i]; vls[i] = vlist[b * 512 + i]; }
  __syncthreads();
  const float* xb = x + (size_t)b * 512 * 64;

  int rn[2][4]; bool vr[2][4];
#pragma unroll
  for (int g = 0; g < 2; ++g)
#pragma unroll
    for (int i = 0; i < 4; ++i) {
      const int c = rbase + w * 8 + g * 4 + i;
      vr[g][i] = (c < nv);
      rn[g][i] = vls[c < nv ? c : 0];
    }

  float accd[2][4][8];
#pragma unroll
  for (int g = 0; g < 2; ++g)
#pragma unroll
    for (int i = 0; i < 4; ++i)
#pragma unroll
      for (int j = 0; j < 8; ++j) accd[g][i][j] = 0.f;

#pragma unroll
  for (int cb = 0; cb < 4; ++cb) {
    if (cb * 128 < nv) {  // uniform
      __syncthreads();
      {
        const int f4 = (t & 15) * 4;
        const int cl0 = t >> 4;
#pragma unroll
        for (int p = 0; p < 8; ++p) {
          const int cl = cl0 + p * 16;
          const int c = cb * 128 + cl;
          if (c < nv) {
            const int row = vls[c];
            *(float4*)(xc + cl * 68 + f4) = *(const float4*)(xb + (size_t)row * 64 + f4);
          }
        }
      }
      __syncthreads();
#pragma unroll
      for (int g = 0; g < 2; ++g) {
        for (int fc = 0; fc < 16; ++fc) {
          float4 xn4[4];
#pragma unroll
          for (int i = 0; i < 4; ++i)
            xn4[i] = *(const float4*)(xb + (size_t)rn[g][i] * 64 + fc * 4);
#pragma unroll
          for (int j2 = 0; j2 < 2; ++j2) {
            if (cb * 128 + j2 * 64 < nv) {  // uniform
              const float4 xm = *(const float4*)(xc + (j2 * 64 + lane) * 68 + fc * 4);
#pragma unroll
              for (int i = 0; i < 4; ++i) {
                float a = accd[g][i][cb * 2 + j2];
                a = fmaf(xn4[i].x, xm.x, a);
                a = fmaf(xn4[i].y, xm.y, a);
                a = fmaf(xn4[i].z, xm.z, a);
                a = fmaf(xn4[i].w, xm.w, a);
                accd[g][i][cb * 2 + j2] = a;
              }
            }
          }
        }
      }
    }
  }

  // selection: static 8 slots, dead slots carry ~0ull keys
#pragma unroll
  for (int g = 0; g < 2; ++g) {
#pragma unroll
    for (int i = 0; i < 4; ++i) {
      if (!vr[g][i]) continue;
      const int n = rn[g][i];
      const float sqn = sqs[n];
      unsigned long long key[8];
#pragma unroll
      for (int j = 0; j < 8; ++j) {
        const int c = j * 64 + lane;
        if (c < nv) {
          const int mj = vls[c];
          const float d = fabsf(sqn + sqs[mj] - 2.f * accd[g][i][j]);
          key[j] = (((unsigned long long)__float_as_uint(d)) << 32) | (unsigned)mj;
        } else key[j] = ~0ull;
      }
      int mywin = n;
      for (int ts = 0; ts < 17; ++ts) {
        unsigned long long lmin = ~0ull;
#pragma unroll
        for (int j = 0; j < 8; ++j) lmin = key[j] < lmin ? key[j] : lmin;
        const unsigned long long wmin = wave_min_u64(lmin);
        if (ts > 0 && lane == ts - 1)
          mywin = (wmin == ~0ull) ? n : (int)(unsigned)(wmin & 0xffffffffull);
#pragma unroll
        for (int j = 0; j < 8; ++j) if (key[j] == wmin) key[j] = ~0ull;
      }
      if (lane < 16) idxg[((size_t)b * 512 + n) * 16 + lane] = mywin;
    }
  }
}

// ---------------- Kernel C: edge MLP over COMPACTED valid receivers ----------------
// All senders from kknn are valid => emask==1, cnt==16 (exact for nv>=17).
// L1: A' = [E_hi | E_lo] from xhi/xlo planes (single 16B loads), B' = [W1_hi; W1_hi]
// L2: A' = [H_hi | H_hi] via per-wave hfrag, B' = [W2_hi; W2_lo]
__global__ void __launch_bounds__(256) kedge(const bf16_t* __restrict__ xhi,
    const bf16_t* __restrict__ xlo, const int* __restrict__ idxg,
    const int* __restrict__ vlist, const int* __restrict__ vcnt,
    const bf16_t* __restrict__ W1p, const bf16_t* __restrict__ W2p,
    const float* __restrict__ be1, const float* __restrict__ be2,
    float* __restrict__ pooled) {
  const int bb = blockIdx.x >> 6, tile = blockIdx.x & 63;
  const int nv = vcnt[bb];
  if (tile * 8 >= nv) return;  // block-uniform, before any barrier
  __shared__ __align__(16) bf16_t slab[4096];          // 8 KB
  __shared__ __align__(16) bf16_t hfrag[4][2][2048];   // 32 KB
  const int t = threadIdx.x, lane = t & 63, w = t >> 6;
  const int q = lane >> 4, e = lane & 15;

  int gid[2]; bool act[2]; int sv[2];
#pragma unroll
  for (int u = 0; u < 2; ++u) {
    const int slot = tile * 8 + w * 2 + u;
    act[u] = (slot < nv);
    gid[u] = act[u] ? (bb * 512 + vlist[bb * 512 + slot]) : 0;
    sv[u] = act[u] ? idxg[(size_t)gid[u] * 16 + e] : 0;
  }

  f32x4 acc[2][8];
#pragma unroll
  for (int u = 0; u < 2; ++u)
#pragma unroll
    for (int nt = 0; nt < 8; ++nt) acc[u][nt] = zero4();

  // ---- Layer 1 ----
  for (int s = 0; s < 8; ++s) {
    __syncthreads();
    {
      const uint4* src = (const uint4*)(W1p + (size_t)s * 4096);
      uint4* dst = (uint4*)slab;
      for (int i = t; i < 512; i += 256) dst[i] = src[i];
    }
    __syncthreads();
    const bool wantlo = (s >= 4);
    const int sr = s & 3, half = sr >> 1, inner = sr & 1;
    const int col = inner * 32 + q * 8;
    const bf16_t* plane = wantlo ? xlo : xhi;
    bf16x8 af[2];
#pragma unroll
    for (int u = 0; u < 2; ++u) {
      if (act[u]) {
        const int row = half ? (bb * 512 + sv[u]) : gid[u];
        af[u] = *(const bf16x8*)(plane + (size_t)row * 64 + col);
      }
    }
#pragma unroll
    for (int nt = 0; nt < 8; ++nt) {
      const bf16x8 bfv = *(const bf16x8*)(slab + (nt * 64 + lane) * 8);
#pragma unroll
      for (int u = 0; u < 2; ++u)
        if (act[u]) acc[u][nt] = __builtin_amdgcn_mfma_f32_16x16x32_bf16(af[u], bfv, acc[u][nt], 0, 0, 0);
    }
  }

  // ---- Epilogue 1: bias+relu -> bf16 hi -> per-wave lane-linear A-frag buffer ----
#pragma unroll
  for (int u = 0; u < 2; ++u) {
    if (act[u]) {
#pragma unroll
      for (int nt = 0; nt < 8; ++nt) {
        const int cc = nt * 16 + e;
        const float bv = be1[cc];
        const int base = ((cc >> 5) * 64 + (q * 4) + 16 * ((cc >> 3) & 3)) * 8 + (cc & 7);
#pragma unroll
        for (int r = 0; r < 4; ++r) {
          float h = fmaxf(acc[u][nt][r] + bv, 0.f);
          hfrag[w][u][base + r * 8] = f2b(h);
        }
      }
    }
  }

  // ---- Layer 2 ----
#pragma unroll
  for (int u = 0; u < 2; ++u)
#pragma unroll
    for (int nt = 0; nt < 8; ++nt) acc[u][nt] = zero4();

  for (int s = 0; s < 8; ++s) {
    __syncthreads();
    {
      const uint4* src = (const uint4*)(W2p + (size_t)s * 4096);
      uint4* dst = (uint4*)slab;
      for (int i = t; i < 512; i += 256) dst[i] = src[i];
    }
    __syncthreads();
    const int f = s & 3;
    bf16x8 af[2];
#pragma unroll
    for (int u = 0; u < 2; ++u)
      if (act[u]) af[u] = *(const bf16x8*)(&hfrag[w][u][(f * 64 + lane) * 8]);
#pragma unroll
    for (int nt = 0; nt < 8; ++nt) {
      const bf16x8 bfv = *(const bf16x8*)(slab + (nt * 64 + lane) * 8);
#pragma unroll
      for (int u = 0; u < 2; ++u)
        if (act[u]) acc[u][nt] = __builtin_amdgcn_mfma_f32_16x16x32_bf16(af[u], bfv, acc[u][nt], 0, 0, 0);
    }
  }

  // ---- Epilogue 2: bias+relu, mean over 16 edges (cnt==16 exactly) ----
#pragma unroll
  for (int u = 0; u < 2; ++u) {
    if (act[u]) {
#pragma unroll
      for (int nt = 0; nt < 8; ++nt) {
        const float bv = be2[nt * 16 + e];
        float part = 0.f;
#pragma unroll
        for (int r = 0; r < 4; ++r) part += fmaxf(acc[u][nt][r] + bv, 0.f);
        part += __shfl_xor(part, 16, 64);
        part += __shfl_xor(part, 32, 64);
        if (lane < 16) pooled[(size_t)gid[u] * 128 + nt * 16 + lane] = part * 0.0625f;
      }
    }
  }
}

// ---------------- Kernel D: node MLP (wave = 2 tiles of 16 nodes) ------------------
// Masked nodes: x rows are 0, pooled rows may hold finite ws-poison; out is *mask -> 0.
__global__ void __launch_bounds__(256) knode(const float* __restrict__ x,
    const float* __restrict__ pooled, const int* __restrict__ mask,
    const bf16_t* __restrict__ Wn1p, const bf16_t* __restrict__ Wn2p,
    const float* __restrict__ bn1, const float* __restrict__ bn2,
    float* __restrict__ out) {
  __shared__ __align__(16) bf16_t slab[4096];          // 8 KB
  __shared__ __align__(16) bf16_t hfrag[4][2][2048];   // 32 KB
  const int t = threadIdx.x, lane = t & 63, w = t >> 6;
  const int q = lane >> 4, e = lane & 15;
  int nodebase[2];
#pragma unroll
  for (int u = 0; u < 2; ++u) nodebase[u] = (blockIdx.x * 8 + w * 2 + u) * 16;

  f32x4 acc[2][8];
#pragma unroll
  for (int u = 0; u < 2; ++u)
#pragma unroll
    for (int nt = 0; nt < 8; ++nt) acc[u][nt] = zero4();

  // ---- Layer 1 (12 slabs) ----
  for (int s = 0; s < 12; ++s) {
    __syncthreads();
    {
      const uint4* src = (const uint4*)(Wn1p + (size_t)s * 4096);
      uint4* dst = (uint4*)slab;
      for (int i = t; i < 512; i += 256) dst[i] = src[i];
    }
    __syncthreads();
    const bool wantlo = (s >= 6);
    const int sr = wantlo ? (s - 6) : s;
    const int col = sr * 32 + q * 8;  // [0,192); region uniform per s
    bf16x8 af[2];
#pragma unroll
    for (int u = 0; u < 2; ++u) {
      const int node = nodebase[u] + e;
      const float* p = (col < 64) ? (x + (size_t)node * 64 + col)
                                  : (pooled + (size_t)node * 128 + (col - 64));
      af[u] = make_frag(p, wantlo);
    }
#pragma unroll
    for (int nt = 0; nt < 8; ++nt) {
      const bf16x8 bfv = *(const bf16x8*)(slab + (nt * 64 + lane) * 8);
#pragma unroll
      for (int u = 0; u < 2; ++u)
        acc[u][nt] = __builtin_amdgcn_mfma_f32_16x16x32_bf16(af[u], bfv, acc[u][nt], 0, 0, 0);
    }
  }

  // ---- Epilogue 1 ----
#pragma unroll
  for (int u = 0; u < 2; ++u) {
#pragma unroll
    for (int nt = 0; nt < 8; ++nt) {
      const int cc = nt * 16 + e;
      const float bv = bn1[cc];
      const int base = ((cc >> 5) * 64 + (q * 4) + 16 * ((cc >> 3) & 3)) * 8 + (cc & 7);
#pragma unroll
      for (int r = 0; r < 4; ++r) {
        float h = fmaxf(acc[u][nt][r] + bv, 0.f);
        hfrag[w][u][base + r * 8] = f2b(h);
      }
    }
  }

  // ---- Layer 2 (8 slabs of 4 KB, N=64 -> 4 ntiles) ----
  f32x4 acc2[2][4];
#pragma unroll
  for (int u = 0; u < 2; ++u)
#pragma unroll
    for (int nt = 0; nt < 4; ++nt) acc2[u][nt] = zero4();

  for (int s = 0; s < 8; ++s) {
    __syncthreads();
    {
      const uint4* src = (const uint4*)(Wn2p + (size_t)s * 2048);
      uint4* dst = (uint4*)slab;
      for (int i = t; i < 256; i += 256) dst[i] = src[i];
    }
    __syncthreads();
    const int f = s & 3;
    bf16x8 af[2];
#pragma unroll
    for (int u = 0; u < 2; ++u)
      af[u] = *(const bf16x8*)(&hfrag[w][u][(f * 64 + lane) * 8]);
#pragma unroll
    for (int nt = 0; nt < 4; ++nt) {
      const bf16x8 bfv = *(const bf16x8*)(slab + (nt * 64 + lane) * 8);
#pragma unroll
      for (int u = 0; u < 2; ++u)
        acc2[u][nt] = __builtin_amdgcn_mfma_f32_16x16x32_bf16(af[u], bfv, acc2[u][nt], 0, 0, 0);
    }
  }

  // ---- Final: + bn2, * mask, store ----
#pragma unroll
  for (int u = 0; u < 2; ++u) {
    int mm[4];
#pragma unroll
    for (int r = 0; r < 4; ++r) mm[r] = mask[nodebase[u] + q * 4 + r];
#pragma unroll
    for (int nt = 0; nt < 4; ++nt) {
      const float bv = bn2[nt * 16 + e];
#pragma unroll
      for (int r = 0; r < 4; ++r) {
        const int node = nodebase[u] + q * 4 + r;
        out[(size_t)node * 64 + nt * 16 + e] = (acc2[u][nt][r] + bv) * (float)mm[r];
      }
    }
  }
}

// ---------------- Launch ----------------
extern "C" void kernel_launch(void* const* d_in, const int* in_sizes, int n_in,
                              void* d_out, int out_size, void* d_ws, size_t ws_size,
                              hipStream_t stream) {
  const float* nodes = (const float*)d_in[0];
  const int*   mask  = (const int*)d_in[1];
  const float* We1   = (const float*)d_in[2];
  const float* be1   = (const float*)d_in[3];
  const float* We2   = (const float*)d_in[4];
  const float* be2   = (const float*)d_in[5];
  const float* Wn1   = (const float*)d_in[6];
  const float* bn1   = (const float*)d_in[7];
  const float* Wn2   = (const float*)d_in[8];
  const float* bn2   = (const float*)d_in[9];
  float* out = (float*)d_out;

  char* p = (char*)d_ws;
  auto alloc = [&](size_t bytes) -> char* {
    char* r = p;
    p += (bytes + 255) & ~(size_t)255;
    return r;
  };
  float*  x      = (float*)alloc((size_t)32768 * 64 * 4);
  bf16_t* xhi    = (bf16_t*)alloc((size_t)32768 * 64 * 2);
  bf16_t* xlo    = (bf16_t*)alloc((size_t)32768 * 64 * 2);
  float*  sq     = (float*)alloc((size_t)32768 * 4);
  int*    vlist  = (int*)alloc((size_t)32768 * 4);
  int*    vcnt   = (int*)alloc((size_t)64 * 4);
  int*    idxg   = (int*)alloc((size_t)32768 * 16 * 4);
  float*  pooled = (float*)alloc((size_t)32768 * 128 * 4);
  bf16_t* W1p    = (bf16_t*)alloc((size_t)8 * 8 * 64 * 8 * 2);
  bf16_t* W2p    = (bf16_t*)alloc((size_t)8 * 8 * 64 * 8 * 2);
  bf16_t* Wn1p   = (bf16_t*)alloc((size_t)12 * 8 * 64 * 8 * 2);
  bf16_t* Wn2p   = (bf16_t*)alloc((size_t)8 * 4 * 64 * 8 * 2);
  if ((size_t)(p - (char*)d_ws) > ws_size) return;  // workspace too small -> loud failure

  kpack<<<64, 256, 0, stream>>>(We1, We2, Wn1, Wn2, W1p, W2p, Wn1p, Wn2p);
  kprep<<<64, 256, 0, stream>>>(nodes, mask, x, xhi, xlo, sq, vlist, vcnt);
  kknn<<<1024, 256, 0, stream>>>(x, sq, vlist, vcnt, idxg);
  kedge<<<4096, 256, 0, stream>>>(xhi, xlo, idxg, vlist, vcnt, W1p, W2p, be1, be2, pooled);
  knode<<<256, 256, 0, stream>>>(x, pooled, mask, Wn1p, Wn2p, bn1, bn2, out);
}

// Round 4
// 390.693 us; speedup vs baseline: 1.4968x; 1.0621x over previous
//
#include <hip/hip_runtime.h>

#define DI __device__ __forceinline__

typedef __bf16 bf16_t;
typedef __bf16 bf16x4 __attribute__((ext_vector_type(4)));
typedef __bf16 bf16x8 __attribute__((ext_vector_type(8)));
typedef float f32x4 __attribute__((ext_vector_type(4)));

// Problem constants
// B=64, N=512, F=64, H=128, FO=64, K=16
// Edge MLP: E(16x128) @ We1(128x128) -> relu -> @ We2(128x128) -> relu -> mean -> pooled(128)
// Node MLP: [x|pooled](192) @ Wn1(192x128) -> relu -> @ Wn2(128x64) -> out, * mask

DI bf16_t f2b(float f) {
  unsigned u = __float_as_uint(f);
  unsigned r = (u + 0x7fffu + ((u >> 16) & 1u)) >> 16;
  return __builtin_bit_cast(bf16_t, (unsigned short)r);
}
DI float b2f(bf16_t h) {
  return __uint_as_float(((unsigned)__builtin_bit_cast(unsigned short, h)) << 16);
}
DI f32x4 zero4() { f32x4 z = {0.f, 0.f, 0.f, 0.f}; return z; }
DI unsigned umin2(unsigned a, unsigned b) { return a < b ? a : b; }

DI bf16x8 make_frag(const float* p, bool wantlo) {
  float4 v0 = *(const float4*)p;
  float4 v1 = *(const float4*)(p + 4);
  float vv[8] = {v0.x, v0.y, v0.z, v0.w, v1.x, v1.y, v1.z, v1.w};
  bf16x8 a;
#pragma unroll
  for (int j = 0; j < 8; ++j) {
    bf16_t hi = f2b(vv[j]);
    a[j] = wantlo ? f2b(vv[j] - b2f(hi)) : hi;
  }
  return a;
}

// Wave64 u32 min, result wave-uniform. 4 intra-row DPP steps (~4cyc each,
// VALU pipe — no LDS latency) + 4 readlanes + scalar mins.
DI unsigned wave_min_u32(unsigned v) {
  unsigned t;
  t = (unsigned)__builtin_amdgcn_update_dpp(0, (int)v, 0xB1, 0xF, 0xF, true);  // quad_perm(1,0,3,2)
  v = umin2(v, t);
  t = (unsigned)__builtin_amdgcn_update_dpp(0, (int)v, 0x4E, 0xF, 0xF, true);  // quad_perm(2,3,0,1)
  v = umin2(v, t);
  t = (unsigned)__builtin_amdgcn_update_dpp(0, (int)v, 0x141, 0xF, 0xF, true); // row_half_mirror
  v = umin2(v, t);
  t = (unsigned)__builtin_amdgcn_update_dpp(0, (int)v, 0x140, 0xF, 0xF, true); // row_mirror
  v = umin2(v, t);
  unsigned a = (unsigned)__builtin_amdgcn_readlane((int)v, 0);
  unsigned b = (unsigned)__builtin_amdgcn_readlane((int)v, 16);
  unsigned c = (unsigned)__builtin_amdgcn_readlane((int)v, 32);
  unsigned d = (unsigned)__builtin_amdgcn_readlane((int)v, 48);
  return umin2(umin2(a, b), umin2(c, d));
}

// ---------------- Kernel P: pack weights into split-bf16 MFMA B-fragment layout ----
__global__ void kpack(const float* __restrict__ We1, const float* __restrict__ We2,
                      const float* __restrict__ Wn1, const float* __restrict__ Wn2,
                      bf16_t* __restrict__ W1p, bf16_t* __restrict__ W2p,
                      bf16_t* __restrict__ Wn1p, bf16_t* __restrict__ Wn2p) {
  int p = blockIdx.x * 256 + threadIdx.x;  // 0..16383
  const float* W; bf16_t* dst; int K, Nn, local, mode;
  if (p < 4096)       { W = We1; dst = W1p;  K = 128; Nn = 128; mode = 0; local = p; }
  else if (p < 8192)  { W = We2; dst = W2p;  K = 128; Nn = 128; mode = 1; local = p - 4096; }
  else if (p < 14336) { W = Wn1; dst = Wn1p; K = 192; Nn = 128; mode = 0; local = p - 8192; }
  else                { W = Wn2; dst = Wn2p; K = 128; Nn = 64;  mode = 1; local = p - 14336; }
  int lane = local & 63;
  int nnt = (Nn >> 4);
  int chunk = local >> 6;
  int nt = chunk % nnt;
  int s = chunk / nnt;
  int n = nt * 16 + (lane & 15);
  int kbase = s * 32 + ((lane >> 4) * 8);
  bf16x8 v;
#pragma unroll
  for (int j = 0; j < 8; ++j) {
    int kp = kbase + j;
    int region = kp / K;
    int kk = kp - region * K;
    float w = W[kk * Nn + n];
    bf16_t hi = f2b(w);
    v[j] = (mode == 1 && region == 1) ? f2b(w - b2f(hi)) : hi;
  }
  *(bf16x8*)(dst + (size_t)local * 8) = v;
}

// ---------------- Kernel A: x, xhi/xlo planes, sq, per-batch compaction ------------
__global__ void __launch_bounds__(256) kprep(const float* __restrict__ nodes,
    const int* __restrict__ mask, float* __restrict__ x,
    bf16_t* __restrict__ xhi, bf16_t* __restrict__ xlo,
    float* __restrict__ sq, int* __restrict__ vlist, int* __restrict__ vcnt) {
  const int b = blockIdx.x, t = threadIdx.x, lane = t & 63, w = t >> 6;
  __shared__ int cnts[8];
  __shared__ int basep[8];
  unsigned long long bal[2]; int flag[2];
#pragma unroll
  for (int h = 0; h < 2; ++h) {
    const int n = h * 256 + t;
    const size_t ro = (size_t)(b * 512 + n) * 64;
    const int mk = mask[b * 512 + n];
    const float fm = (float)mk;
    float s = 0.f;
#pragma unroll
    for (int c = 0; c < 64; c += 4) {
      float4 v = *(const float4*)(nodes + ro + c);
      v.x *= fm; v.y *= fm; v.z *= fm; v.w *= fm;
      *(float4*)(x + ro + c) = v;
      float vv[4] = {v.x, v.y, v.z, v.w};
      bf16x4 hh, ll;
#pragma unroll
      for (int k = 0; k < 4; ++k) {
        bf16_t hi = f2b(vv[k]);
        hh[k] = hi;
        ll[k] = f2b(vv[k] - b2f(hi));
      }
      *(bf16x4*)(xhi + ro + c) = hh;
      *(bf16x4*)(xlo + ro + c) = ll;
      s += v.x * v.x + v.y * v.y + v.z * v.z + v.w * v.w;
    }
    sq[b * 512 + n] = s;
    flag[h] = (mk != 0);
    bal[h] = __ballot(flag[h]);
    if (lane == 0) cnts[h * 4 + w] = __popcll(bal[h]);
  }
  __syncthreads();
  if (t == 0) {
    int a = 0;
    for (int c = 0; c < 8; ++c) { basep[c] = a; a += cnts[c]; }
    vcnt[b] = a;
  }
  __syncthreads();
#pragma unroll
  for (int h = 0; h < 2; ++h) {
    if (flag[h]) {
      const unsigned long long lt = (lane == 0) ? 0ull : (~0ull >> (64 - lane));
      const int pos = basep[h * 4 + w] + __popcll(bal[h] & lt);
      vlist[b * 512 + pos] = h * 256 + t;
    }
  }
}

// ---------------- Kernel B: distances + top-17 over compacted candidates -----------
// Grid: 64 batches x 32 tiles of 16 receiver slots (b = blockIdx&63 so active tiles
// dispatch first). Wave = 4 receivers. Receiver rows staged in LDS (xr) once;
// candidates staged in 64-row chunks (xc, stride 68 -> b128 at the phase floor).
// Selection = 17 extraction rounds; per round: DPP wave-min over dist bits, then
// DPP wave-min over node-ids among dist-matching slots (== ascending (dist,idx)
// order of jax.lax.top_k(-dist,K+1)), drop rank 0 (self).
__global__ void __launch_bounds__(256) kknn(const float* __restrict__ x,
    const float* __restrict__ sq, const int* __restrict__ vlist,
    const int* __restrict__ vcnt, int* __restrict__ idxg) {
  const int b = blockIdx.x & 63, tile = blockIdx.x >> 6;
  const int nv = vcnt[b];
  if (tile * 16 >= nv) return;  // block-uniform, before any barrier
  const int t = threadIdx.x, lane = t & 63, w = t >> 6;
  __shared__ float sqs[512];
  __shared__ int vls[512];
  __shared__ __align__(16) float xr[16 * 64];   // 4 KB receiver rows
  __shared__ __align__(16) float xc[64 * 68];   // 17.4 KB candidate chunk
  for (int i = t; i < 512; i += 256) { sqs[i] = sq[b * 512 + i]; vls[i] = vlist[b * 512 + i]; }
  __syncthreads();
  const float* xb = x + (size_t)b * 512 * 64;
  // stage 16 receiver rows: 16 threads per row
  {
    const int r = t >> 4, f4 = (t & 15) * 4;
    const int slot = tile * 16 + r;
    const int row = vls[slot < nv ? slot : 0];
    *(float4*)(xr + r * 64 + f4) = *(const float4*)(xb + (size_t)row * 64 + f4);
  }
  int rn[4]; bool vr[4];
#pragma unroll
  for (int i = 0; i < 4; ++i) {
    const int slot = tile * 16 + w * 4 + i;
    vr[i] = (slot < nv);
    rn[i] = vls[slot < nv ? slot : 0];
  }

  float accd[4][8];
#pragma unroll
  for (int i = 0; i < 4; ++i)
#pragma unroll
    for (int j = 0; j < 8; ++j) accd[i][j] = 0.f;

#pragma unroll
  for (int cb = 0; cb < 8; ++cb) {
    if (cb * 64 < nv) {  // uniform
      __syncthreads();
      {
        const int f4 = (t & 15) * 4;
#pragma unroll
        for (int p = 0; p < 4; ++p) {
          const int cl = (t >> 4) + p * 16;
          const int c = cb * 64 + cl;
          if (c < nv)
            *(float4*)(xc + cl * 68 + f4) = *(const float4*)(xb + (size_t)vls[c] * 64 + f4);
        }
      }
      __syncthreads();
#pragma unroll
      for (int fc = 0; fc < 16; ++fc) {
        const float4 xm = *(const float4*)(xc + lane * 68 + fc * 4);
#pragma unroll
        for (int i = 0; i < 4; ++i) {
          const float4 xn = *(const float4*)(xr + (w * 4 + i) * 64 + fc * 4);  // broadcast
          float a = accd[i][cb];
          a = fmaf(xn.x, xm.x, a);
          a = fmaf(xn.y, xm.y, a);
          a = fmaf(xn.z, xm.z, a);
          a = fmaf(xn.w, xm.w, a);
          accd[i][cb] = a;
        }
      }
    }
  }

  // selection: one receiver at a time, all rounds on DPP wave-mins
#pragma unroll
  for (int i = 0; i < 4; ++i) {
    if (!vr[i]) continue;  // wave-uniform
    const int n = rn[i];
    const float sqn = sqs[n];
    unsigned dk[8], mj[8];
#pragma unroll
    for (int j = 0; j < 8; ++j) {
      dk[j] = 0xFFFFFFFFu; mj[j] = 0x7FFFFFFFu;
      if (j * 64 < nv) {  // uniform
        const int c = j * 64 + lane;
        const int m = vls[c < nv ? c : 0];
        const float d = fabsf(sqn + sqs[m] - 2.f * accd[i][j]);
        if (c < nv) { dk[j] = __float_as_uint(d); mj[j] = (unsigned)m; }
      }
    }
    int mywin = n;
    for (int ts = 0; ts < 17; ++ts) {
      unsigned dl = 0xFFFFFFFFu;
#pragma unroll
      for (int j = 0; j < 8; ++j) if (j * 64 < nv) dl = umin2(dl, dk[j]);
      const unsigned dmin = wave_min_u32(dl);
      unsigned il = 0x7FFFFFFFu;
#pragma unroll
      for (int j = 0; j < 8; ++j) if (j * 64 < nv) il = (dk[j] == dmin) ? umin2(il, mj[j]) : il;
      const unsigned imin = wave_min_u32(il);
      if (ts > 0 && lane == ts - 1) mywin = (dmin == 0xFFFFFFFFu) ? n : (int)imin;
#pragma unroll
      for (int j = 0; j < 8; ++j)
        if (j * 64 < nv) { if (dk[j] == dmin && mj[j] == imin) dk[j] = 0xFFFFFFFFu; }
    }
    if (lane < 16) idxg[((size_t)b * 512 + n) * 16 + lane] = mywin;
  }
}

// ---------------- Kernel C: edge MLP over COMPACTED valid receivers ----------------
// Weights staged in 16 KB phases (2 slabs per barrier-pair): 16 barriers total.
// L1: A' = [E_hi | E_lo] from xhi/xlo planes, B' = [W1_hi; W1_hi]
// L2: A' = [H_hi | H_hi] via per-wave hfrag,  B' = [W2_hi; W2_lo]
__global__ void __launch_bounds__(256) kedge(const bf16_t* __restrict__ xhi,
    const bf16_t* __restrict__ xlo, const int* __restrict__ idxg,
    const int* __restrict__ vlist, const int* __restrict__ vcnt,
    const bf16_t* __restrict__ W1p, const bf16_t* __restrict__ W2p,
    const float* __restrict__ be1, const float* __restrict__ be2,
    float* __restrict__ pooled) {
  const int bb = blockIdx.x >> 6, tile = blockIdx.x & 63;
  const int nv = vcnt[bb];
  if (tile * 8 >= nv) return;  // block-uniform, before any barrier
  __shared__ __align__(16) bf16_t wbuf[8192];          // 16 KB: 2 slabs per phase
  __shared__ __align__(16) bf16_t hfrag[4][2][2048];   // 32 KB
  const int t = threadIdx.x, lane = t & 63, w = t >> 6;
  const int q = lane >> 4, e = lane & 15;

  int gid[2]; bool act[2]; int sv[2];
#pragma unroll
  for (int u = 0; u < 2; ++u) {
    const int slot = tile * 8 + w * 2 + u;
    act[u] = (slot < nv);
    gid[u] = act[u] ? (bb * 512 + vlist[bb * 512 + slot]) : 0;
    sv[u] = act[u] ? idxg[(size_t)gid[u] * 16 + e] : 0;
  }

  f32x4 acc[2][8];
#pragma unroll
  for (int u = 0; u < 2; ++u)
#pragma unroll
    for (int nt = 0; nt < 8; ++nt) acc[u][nt] = zero4();

  // ---- Layer 1: 4 phases x 2 slabs ----
  for (int p = 0; p < 4; ++p) {
    __syncthreads();
    {
      const uint4* src = (const uint4*)(W1p + (size_t)p * 8192);
      uint4* dst = (uint4*)wbuf;
#pragma unroll
      for (int i = 0; i < 4; ++i) dst[t + 256 * i] = src[t + 256 * i];
    }
    __syncthreads();
#pragma unroll
    for (int sl = 0; sl < 2; ++sl) {
      const int s = p * 2 + sl;
      const bool wantlo = (s >= 4);
      const int sr = s & 3, half = sr >> 1, inner = sr & 1;
      const int col = inner * 32 + q * 8;
      const bf16_t* plane = wantlo ? xlo : xhi;
      bf16x8 af[2];
#pragma unroll
      for (int u = 0; u < 2; ++u) {
        if (act[u]) {
          const int row = half ? (bb * 512 + sv[u]) : gid[u];
          af[u] = *(const bf16x8*)(plane + (size_t)row * 64 + col);
        }
      }
#pragma unroll
      for (int nt = 0; nt < 8; ++nt) {
        const bf16x8 bfv = *(const bf16x8*)(wbuf + sl * 4096 + (nt * 64 + lane) * 8);
#pragma unroll
        for (int u = 0; u < 2; ++u)
          if (act[u]) acc[u][nt] = __builtin_amdgcn_mfma_f32_16x16x32_bf16(af[u], bfv, acc[u][nt], 0, 0, 0);
      }
    }
  }

  // ---- Epilogue 1: bias+relu -> bf16 hi -> per-wave lane-linear A-frag buffer ----
#pragma unroll
  for (int u = 0; u < 2; ++u) {
    if (act[u]) {
#pragma unroll
      for (int nt = 0; nt < 8; ++nt) {
        const int cc = nt * 16 + e;
        const float bv = be1[cc];
        const int base = ((cc >> 5) * 64 + (q * 4) + 16 * ((cc >> 3) & 3)) * 8 + (cc & 7);
#pragma unroll
        for (int r = 0; r < 4; ++r) {
          float h = fmaxf(acc[u][nt][r] + bv, 0.f);
          hfrag[w][u][base + r * 8] = f2b(h);
        }
      }
    }
  }

  // ---- Layer 2: 4 phases x 2 slabs ----
#pragma unroll
  for (int u = 0; u < 2; ++u)
#pragma unroll
    for (int nt = 0; nt < 8; ++nt) acc[u][nt] = zero4();

  for (int p = 0; p < 4; ++p) {
    __syncthreads();
    {
      const uint4* src = (const uint4*)(W2p + (size_t)p * 8192);
      uint4* dst = (uint4*)wbuf;
#pragma unroll
      for (int i = 0; i < 4; ++i) dst[t + 256 * i] = src[t + 256 * i];
    }
    __syncthreads();
#pragma unroll
    for (int sl = 0; sl < 2; ++sl) {
      const int s = p * 2 + sl;
      const int f = s & 3;
      bf16x8 af[2];
#pragma unroll
      for (int u = 0; u < 2; ++u)
        if (act[u]) af[u] = *(const bf16x8*)(&hfrag[w][u][(f * 64 + lane) * 8]);
#pragma unroll
      for (int nt = 0; nt < 8; ++nt) {
        const bf16x8 bfv = *(const bf16x8*)(wbuf + sl * 4096 + (nt * 64 + lane) * 8);
#pragma unroll
        for (int u = 0; u < 2; ++u)
          if (act[u]) acc[u][nt] = __builtin_amdgcn_mfma_f32_16x16x32_bf16(af[u], bfv, acc[u][nt], 0, 0, 0);
      }
    }
  }

  // ---- Epilogue 2: bias+relu, mean over 16 edges (cnt==16 exactly) ----
#pragma unroll
  for (int u = 0; u < 2; ++u) {
    if (act[u]) {
#pragma unroll
      for (int nt = 0; nt < 8; ++nt) {
        const float bv = be2[nt * 16 + e];
        float part = 0.f;
#pragma unroll
        for (int r = 0; r < 4; ++r) part += fmaxf(acc[u][nt][r] + bv, 0.f);
        part += __shfl_xor(part, 16, 64);
        part += __shfl_xor(part, 32, 64);
        if (lane < 16) pooled[(size_t)gid[u] * 128 + nt * 16 + lane] = part * 0.0625f;
      }
    }
  }
}

// ---------------- Kernel D: node MLP (wave = 2 tiles of 16 nodes) ------------------
// Masked nodes: x rows are 0, pooled rows may hold finite ws-poison; out is *mask -> 0.
__global__ void __launch_bounds__(256) knode(const float* __restrict__ x,
    const float* __restrict__ pooled, const int* __restrict__ mask,
    const bf16_t* __restrict__ Wn1p, const bf16_t* __restrict__ Wn2p,
    const float* __restrict__ bn1, const float* __restrict__ bn2,
    float* __restrict__ out) {
  __shared__ __align__(16) bf16_t slab[4096];          // 8 KB
  __shared__ __align__(16) bf16_t hfrag[4][2][2048];   // 32 KB
  const int t = threadIdx.x, lane = t & 63, w = t >> 6;
  const int q = lane >> 4, e = lane & 15;
  int nodebase[2];
#pragma unroll
  for (int u = 0; u < 2; ++u) nodebase[u] = (blockIdx.x * 8 + w * 2 + u) * 16;

  f32x4 acc[2][8];
#pragma unroll
  for (int u = 0; u < 2; ++u)
#pragma unroll
    for (int nt = 0; nt < 8; ++nt) acc[u][nt] = zero4();

  // ---- Layer 1 (12 slabs) ----
  for (int s = 0; s < 12; ++s) {
    __syncthreads();
    {
      const uint4* src = (const uint4*)(Wn1p + (size_t)s * 4096);
      uint4* dst = (uint4*)slab;
      for (int i = t; i < 512; i += 256) dst[i] = src[i];
    }
    __syncthreads();
    const bool wantlo = (s >= 6);
    const int sr = wantlo ? (s - 6) : s;
    const int col = sr * 32 + q * 8;  // [0,192); region uniform per s
    bf16x8 af[2];
#pragma unroll
    for (int u = 0; u < 2; ++u) {
      const int node = nodebase[u] + e;
      const float* p = (col < 64) ? (x + (size_t)node * 64 + col)
                                  : (pooled + (size_t)node * 128 + (col - 64));
      af[u] = make_frag(p, wantlo);
    }
#pragma unroll
    for (int nt = 0; nt < 8; ++nt) {
      const bf16x8 bfv = *(const bf16x8*)(slab + (nt * 64 + lane) * 8);
#pragma unroll
      for (int u = 0; u < 2; ++u)
        acc[u][nt] = __builtin_amdgcn_mfma_f32_16x16x32_bf16(af[u], bfv, acc[u][nt], 0, 0, 0);
    }
  }

  // ---- Epilogue 1 ----
#pragma unroll
  for (int u = 0; u < 2; ++u) {
#pragma unroll
    for (int nt = 0; nt < 8; ++nt) {
      const int cc = nt * 16 + e;
      const float bv = bn1[cc];
      const int base = ((cc >> 5) * 64 + (q * 4) + 16 * ((cc >> 3) & 3)) * 8 + (cc & 7);
#pragma unroll
      for (int r = 0; r < 4; ++r) {
        float h = fmaxf(acc[u][nt][r] + bv, 0.f);
        hfrag[w][u][base + r * 8] = f2b(h);
      }
    }
  }

  // ---- Layer 2 (8 slabs of 4 KB, N=64 -> 4 ntiles) ----
  f32x4 acc2[2][4];
#pragma unroll
  for (int u = 0; u < 2; ++u)
#pragma unroll
    for (int nt = 0; nt < 4; ++nt) acc2[u][nt] = zero4();

  for (int s = 0; s < 8; ++s) {
    __syncthreads();
    {
      const uint4* src = (const uint4*)(Wn2p + (size_t)s * 2048);
      uint4* dst = (uint4*)slab;
      for (int i = t; i < 256; i += 256) dst[i] = src[i];
    }
    __syncthreads();
    const int f = s & 3;
    bf16x8 af[2];
#pragma unroll
    for (int u = 0; u < 2; ++u)
      af[u] = *(const bf16x8*)(&hfrag[w][u][(f * 64 + lane) * 8]);
#pragma unroll
    for (int nt = 0; nt < 4; ++nt) {
      const bf16x8 bfv = *(const bf16x8*)(slab + (nt * 64 + lane) * 8);
#pragma unroll
      for (int u = 0; u < 2; ++u)
        acc2[u][nt] = __builtin_amdgcn_mfma_f32_16x16x32_bf16(af[u], bfv, acc2[u][nt], 0, 0, 0);
    }
  }

  // ---- Final: + bn2, * mask, store ----
#pragma unroll
  for (int u = 0; u < 2; ++u) {
    int mm[4];
#pragma unroll
    for (int r = 0; r < 4; ++r) mm[r] = mask[nodebase[u] + q * 4 + r];
#pragma unroll
    for (int nt = 0; nt < 4; ++nt) {
      const float bv = bn2[nt * 16 + e];
#pragma unroll
      for (int r = 0; r < 4; ++r) {
        const int node = nodebase[u] + q * 4 + r;
        out[(size_t)node * 64 + nt * 16 + e] = (acc2[u][nt][r] + bv) * (float)mm[r];
      }
    }
  }
}

// ---------------- Launch ----------------
extern "C" void kernel_launch(void* const* d_in, const int* in_sizes, int n_in,
                              void* d_out, int out_size, void* d_ws, size_t ws_size,
                              hipStream_t stream) {
  const float* nodes = (const float*)d_in[0];
  const int*   mask  = (const int*)d_in[1];
  const float* We1   = (const float*)d_in[2];
  const float* be1   = (const float*)d_in[3];
  const float* We2   = (const float*)d_in[4];
  const float* be2   = (const float*)d_in[5];
  const float* Wn1   = (const float*)d_in[6];
  const float* bn1   = (const float*)d_in[7];
  const float* Wn2   = (const float*)d_in[8];
  const float* bn2   = (const float*)d_in[9];
  float* out = (float*)d_out;

  char* p = (char*)d_ws;
  auto alloc = [&](size_t bytes) -> char* {
    char* r = p;
    p += (bytes + 255) & ~(size_t)255;
    return r;
  };
  float*  x      = (float*)alloc((size_t)32768 * 64 * 4);
  bf16_t* xhi    = (bf16_t*)alloc((size_t)32768 * 64 * 2);
  bf16_t* xlo    = (bf16_t*)alloc((size_t)32768 * 64 * 2);
  float*  sq     = (float*)alloc((size_t)32768 * 4);
  int*    vlist  = (int*)alloc((size_t)32768 * 4);
  int*    vcnt   = (int*)alloc((size_t)64 * 4);
  int*    idxg   = (int*)alloc((size_t)32768 * 16 * 4);
  float*  pooled = (float*)alloc((size_t)32768 * 128 * 4);
  bf16_t* W1p    = (bf16_t*)alloc((size_t)8 * 8 * 64 * 8 * 2);
  bf16_t* W2p    = (bf16_t*)alloc((size_t)8 * 8 * 64 * 8 * 2);
  bf16_t* Wn1p   = (bf16_t*)alloc((size_t)12 * 8 * 64 * 8 * 2);
  bf16_t* Wn2p   = (bf16_t*)alloc((size_t)8 * 4 * 64 * 8 * 2);
  if ((size_t)(p - (char*)d_ws) > ws_size) return;  // workspace too small -> loud failure

  kpack<<<64, 256, 0, stream>>>(We1, We2, Wn1, Wn2, W1p, W2p, Wn1p, Wn2p);
  kprep<<<64, 256, 0, stream>>>(nodes, mask, x, xhi, xlo, sq, vlist, vcnt);
  kknn<<<2048, 256, 0, stream>>>(x, sq, vlist, vcnt, idxg);
  kedge<<<4096, 256, 0, stream>>>(xhi, xlo, idxg, vlist, vcnt, W1p, W2p, be1, be2, pooled);
  knode<<<256, 256, 0, stream>>>(x, pooled, mask, Wn1p, Wn2p, bn1, bn2, out);
}